// Round 1
// baseline (441.650 us; speedup 1.0000x reference)
//
#include <hip/hip_runtime.h>
#include <hip/hip_bf16.h>
#include <stdint.h>

#define S   384
#define CM  256
#define CH  32
#define CZ  128
#define BB  256     // MSA depth b = K of GEMM1
#define EPS 1e-5f

typedef __attribute__((ext_vector_type(8))) short bf16x8;   // 8 bf16 = 4 VGPRs
typedef __attribute__((ext_vector_type(4))) float f32x4;

// workspace layout (bytes)
#define OFF_QT    0u                       // [12288][256] bf16 = 6291456  (row = i*32+c, col = b)
#define OFF_KT    6291456u                 // [12288][256] bf16            (row = j*32+d, col = b)
#define OFF_WT    (OFF_KT + 6291456u)      // [64][256] bf16 = 32768
#define OFF_WOT   (OFF_WT + 32768u)        // [128][1024] bf16 = 262144    WoTp[e][d*32+c] = Wo[c*32+d][e]

__device__ __forceinline__ unsigned short f2bf(float x) {
  union { __hip_bfloat16 h; unsigned short u; } v;
  v.h = __float2bfloat16(x);
  return v.u;
}

// async global->LDS, 16B per lane. lds offset wave-uniform; HW scatters lane L to base + L*16.
__device__ __forceinline__ void gload_lds16(const void* g, char* smem, uint32_t lds_off_uniform) {
  uint32_t l32 = (uint32_t)(uintptr_t)(smem + lds_off_uniform);
  __builtin_amdgcn_global_load_lds(
      (const __attribute__((address_space(1))) uint32_t*)(uintptr_t)g,
      (__attribute__((address_space(3))) uint32_t*)(uintptr_t)l32,
      16, 0, 0);
}

// ---------------- K0: prep WT (q|k concat, transposed) and WoTp (transposed + k-reordered) ----------
__global__ void k0_prep(const float* __restrict__ Wq, const float* __restrict__ Wk,
                        const float* __restrict__ Wo,
                        unsigned short* __restrict__ WTg, unsigned short* __restrict__ WoTg) {
  int idx = blockIdx.x * 256 + threadIdx.x;
  if (idx < 64 * 256) {
    int c = idx >> 8, t = idx & 255;
    float v = (c < 32) ? Wq[t * 32 + c] : Wk[t * 32 + (c - 32)];
    WTg[c * 256 + t] = f2bf(v);
  }
  int j = idx - 64 * 256;
  if (j >= 0 && j < 128 * 1024) {
    int e = j >> 10, dc = j & 1023;       // dc = d*32 + c  (stage-2 k order)
    int c = dc & 31, d = dc >> 5;
    WoTg[e * 1024 + dc] = f2bf(Wo[(c * 32 + d) * 128 + e]);
  }
}

// ---------------- K2: fused rmsnorm + projection GEMM, writes qT/kT transposed -----------------------
__global__ __launch_bounds__(256, 2) void k2_proj(const float* __restrict__ m,
                                                  const float* __restrict__ gin,
                                                  const unsigned short* __restrict__ WTg,
                                                  const float* __restrict__ bq,
                                                  const float* __restrict__ bk,
                                                  unsigned short* __restrict__ qT,
                                                  unsigned short* __restrict__ kT) {
  // LDS: A [128][64] bf16 swz @0 (16KB) | WT [64][256] swz @16384 (32KB) |
  //      scl[128] f32 @49152 (512B) | Cbuf [128][72] bf16 @49664 (18KB)
  __shared__ char smem[49664 + 18432] __attribute__((aligned(16)));
  const int tid = threadIdx.x;
  const int w = tid >> 6, lane = tid & 63;
  const int mlo = lane & 15, quad = lane >> 4;
  const int i0 = blockIdx.x * 4, b0 = blockIdx.y * 32;
  float* scl = (float*)(smem + 49152);

  #pragma unroll
  for (int s = 0; s < 8; ++s) {
    int C0 = (w * 8 + s) * 2;
    int c = C0 + (lane >> 5);
    int j = lane & 31;
    int t8 = (j & ~7) | ((j & 7) ^ (c & 7));
    gload_lds16(WTg + c * 256 + t8 * 8, smem, 16384u + (uint32_t)C0 * 512u);
  }

  // phase A: per-row sum of squares (fp32), 2 threads per row, 128 floats each
  const int rowA = tid >> 1, halfA = tid & 1;
  const int growA = (b0 + (rowA >> 2)) * S + i0 + (rowA & 3);
  {
    const float4* p = (const float4*)(m + (size_t)growA * CM + halfA * 128);
    float ss = 0.f;
    #pragma unroll 8
    for (int q4 = 0; q4 < 32; ++q4) {
      float4 x = p[q4];
      ss += x.x * x.x + x.y * x.y + x.z * x.z + x.w * x.w;
    }
    ss += __shfl_xor(ss, 1, 64);
    if (!halfA) scl[rowA] = rsqrtf(ss * (1.f / 256.f) + EPS);
  }

  f32x4 acc[2][4];
  #pragma unroll
  for (int p = 0; p < 2; ++p)
    #pragma unroll
    for (int q = 0; q < 4; ++q) acc[p][q] = (f32x4)0.f;

  for (int kb = 0; kb < 4; ++kb) {
    __syncthreads();
    {
      const int row = tid >> 1, tk0 = (tid & 1) * 32;
      const float4* pB = (const float4*)(m + (size_t)growA * CM + kb * 64 + tk0);
      const float4* pG = (const float4*)(gin + kb * 64 + tk0);
      float sc = scl[row];
      #pragma unroll
      for (int u = 0; u < 4; ++u) {
        float4 x0 = pB[u * 2], x1 = pB[u * 2 + 1];
        float4 g0 = pG[u * 2], g1 = pG[u * 2 + 1];
        union { unsigned short h[8]; int4 q; } pk;
        pk.h[0] = f2bf(x0.x * sc * g0.x); pk.h[1] = f2bf(x0.y * sc * g0.y);
        pk.h[2] = f2bf(x0.z * sc * g0.z); pk.h[3] = f2bf(x0.w * sc * g0.w);
        pk.h[4] = f2bf(x1.x * sc * g1.x); pk.h[5] = f2bf(x1.y * sc * g1.y);
        pk.h[6] = f2bf(x1.z * sc * g1.z); pk.h[7] = f2bf(x1.w * sc * g1.w);
        int blkid = (((tid & 1) * 4 + u) ^ (row & 7));
        *(int4*)(smem + row * 128 + blkid * 16) = pk.q;
      }
    }
    __syncthreads();
    #pragma unroll
    for (int ks = 0; ks < 2; ++ks) {
      bf16x8 af[2], bfr[4];
      int k8 = ks * 4 + quad;
      #pragma unroll
      for (int fm = 0; fm < 2; ++fm) {
        int mm = w * 32 + fm * 16 + mlo;
        af[fm] = *(const bf16x8*)(smem + mm * 128 + ((k8 ^ (mm & 7)) * 16));
      }
      #pragma unroll
      for (int fn = 0; fn < 4; ++fn) {
        int c = fn * 16 + mlo;
        int t8 = kb * 8 + ks * 4 + quad;
        bfr[fn] = *(const bf16x8*)(smem + 16384 + c * 512 + (((t8 & ~7) | ((t8 & 7) ^ (c & 7))) * 16));
      }
      #pragma unroll
      for (int fm = 0; fm < 2; ++fm)
        #pragma unroll
        for (int fn = 0; fn < 4; ++fn)
          acc[fm][fn] = __builtin_amdgcn_mfma_f32_16x16x32_bf16(af[fm], bfr[fn], acc[fm][fn], 0, 0, 0);
    }
  }
  __syncthreads();
  unsigned short* Cl = (unsigned short*)(smem + 49664);
  #pragma unroll
  for (int fm = 0; fm < 2; ++fm)
    #pragma unroll
    for (int fn = 0; fn < 4; ++fn) {
      int cc = fn * 16 + mlo;
      float bias = (cc < 32) ? bq[cc] : bk[cc - 32];
      #pragma unroll
      for (int r = 0; r < 4; ++r) {
        int rr = w * 32 + fm * 16 + quad * 4 + r;
        Cl[rr * 72 + cc] = f2bf(acc[fm][fn][r] + bias);
      }
    }
  __syncthreads();
  {
    int il = tid >> 6, cc = tid & 63;
    unsigned short* dst = (cc < 32) ? (qT + ((i0 + il) * 32 + cc) * BB + b0)
                                    : (kT + ((i0 + il) * 32 + (cc - 32)) * BB + b0);
    #pragma unroll
    for (int v = 0; v < 4; ++v) {
      union { unsigned short h[8]; int4 q; } u;
      #pragma unroll
      for (int x = 0; x < 8; ++x) u.h[x] = Cl[((v * 8 + x) * 4 + il) * 72 + cc];
      *(int4*)(dst + v * 8) = u.q;
    }
  }
}

// ---------------- K3: 256x128 O-tile GEMM -> @Wo + bo -> rmsnorm -> z -------------------------------
// 512 threads = 8 waves. GEMM1: wave grid 4(m) x 2(n), wave-tile 64x64, frags 4x4.
// Pipeline: A single-buffered but fully pre-read to regs before overwrite; B double-buffered.
// Stage loads for kb+1 are in flight across the 8 B-frag ds_reads + 32 MFMAs (counted-wait effect:
// the vmcnt drain sits at the END-of-iteration barrier, not between stage and compute).
// Stage 2: waves as 4 e-groups x 2 k2-halves, 32x32 wave tiles -> each O ds_read feeds 2 MFMAs
// (halves stage-2 LDS reads); f32 partial sums exchanged via LDS.
__global__ __launch_bounds__(512, 4) void k3_fused(const unsigned short* __restrict__ qT,
                                                   const unsigned short* __restrict__ kT,
                                                   const unsigned short* __restrict__ WoTp,
                                                   const float* __restrict__ bo,
                                                   const float* __restrict__ gout,
                                                   float* __restrict__ out) {
  // LDS 64KB: GEMM1: A-tile [256][64] swz @0 (32KB) | B-tile x2 [128][64] swz @32768/@49152 (16KB each).
  // After GEMM1 the whole 64KB aliases O_lds [32 ij][1024 k2'] bf16 (k2' = d*32+c, swizzled).
  // After stage-2 reads complete, [0,16896) aliases part[4][32][33] f32; red/scl above that.
  __shared__ char smem[65536] __attribute__((aligned(16)));
  const int tid = threadIdx.x;
  const int w = tid >> 6, lane = tid & 63;
  const int wm = w & 3, wn = w >> 2;          // GEMM1 wave grid 4 (m) x 2 (n)
  const int mlo = lane & 15, quad = lane >> 4;

  // XCD-aware swizzle: consecutive blockIdx round-robin XCDs; give each XCD a contiguous
  // 48(ti) x 12(tj) band so kT-band (768KB) + WoTp (256KB) stay L2-resident per XCD.
  const int bid = blockIdx.x;                 // 0..4607
  const int xcd = bid & 7, idx = bid >> 3;    // idx 0..575
  const int ti = idx / 12;                    // 0..47  (A-panel reused by 12 consecutive blocks)
  const int tj = xcd * 12 + (idx % 12);       // 0..95

  f32x4 acc[4][4];
  #pragma unroll
  for (int p = 0; p < 4; ++p)
    #pragma unroll
    for (int q = 0; q < 4; ++q) acc[p][q] = (f32x4)0.f;

  // -------- GEMM1: O[m][n] = sum_b qT[ti*256+m][b] * kT[tj*128+n][b], K=256, BK=64 --------
  auto stageA = [&](int kb) {
    #pragma unroll
    for (int s = 0; s < 4; ++s) {            // A-tile: wave w stages rows [w*32, w*32+32)
      int r = w * 32 + s * 8 + (lane >> 3);
      int k8 = (lane & 7) ^ (r & 7);
      gload_lds16(qT + (ti * 256 + r) * BB + kb * 64 + k8 * 8, smem, (uint32_t)(w * 32 + s * 8) * 128u);
    }
  };
  auto stageB = [&](int kb, int bsel) {
    #pragma unroll
    for (int s = 0; s < 2; ++s) {            // B-tile: wave w stages rows [w*16, w*16+16)
      int r = w * 16 + s * 8 + (lane >> 3);
      int k8 = (lane & 7) ^ (r & 7);
      gload_lds16(kT + (tj * 128 + r) * BB + kb * 64 + k8 * 8, smem,
                  32768u + (uint32_t)bsel * 16384u + (uint32_t)(w * 16 + s * 8) * 128u);
    }
  };

  stageA(0); stageB(0, 0);
  __syncthreads();                           // implicit vmcnt(0) drain: kb=0 tiles landed

  for (int kb = 0; kb < 4; ++kb) {
    const int bsel = kb & 1;
    // pre-read ALL A-frags for this kb into regs (A buffer about to be overwritten)
    bf16x8 af2[2][4];
    #pragma unroll
    for (int ks = 0; ks < 2; ++ks)
      #pragma unroll
      for (int f = 0; f < 4; ++f) {
        int k8 = ks * 4 + quad;
        int mm = wm * 64 + f * 16 + mlo;
        af2[ks][f] = *(const bf16x8*)(smem + mm * 128 + ((k8 ^ (mm & 7)) * 16));
      }
    __syncthreads();                         // implicit lgkmcnt(0): all waves' A-reads in regs
    if (kb < 3) { stageA(kb + 1); stageB(kb + 1, bsel ^ 1); }  // in flight across MFMAs below
    #pragma unroll
    for (int ks = 0; ks < 2; ++ks) {
      bf16x8 bfr[4];
      int k8 = ks * 4 + quad;
      #pragma unroll
      for (int f = 0; f < 4; ++f) {
        int nn = wn * 64 + f * 16 + mlo;
        bfr[f] = *(const bf16x8*)(smem + 32768 + bsel * 16384 + nn * 128 + ((k8 ^ (nn & 7)) * 16));
      }
      #pragma unroll
      for (int fm = 0; fm < 4; ++fm)
        #pragma unroll
        for (int fn = 0; fn < 4; ++fn)
          acc[fm][fn] = __builtin_amdgcn_mfma_f32_16x16x32_bf16(af2[ks][fm], bfr[fn], acc[fm][fn], 0, 0, 0);
    }
    __syncthreads();                         // implicit vmcnt(0): kb+1 tiles landed (hidden by MFMAs)
  }

  // -------- O (C-layout regs) -> O_lds[ij][k2'] bf16, k2' = d*32 + c; packed 8B writes --------
  #pragma unroll
  for (int fm = 0; fm < 4; ++fm)
    #pragma unroll
    for (int fn = 0; fn < 4; ++fn) {
      int col = wn * 64 + fn * 16 + mlo;                 // n = jloc*32 + d  (0..127)
      int row0 = wm * 64 + fm * 16 + quad * 4;           // m = iloc*32 + c  (0..255)
      int ij = (row0 >> 5) * 4 + (col >> 5);             // iloc*4 + jloc    (0..31)
      int k20 = (col & 31) * 32 + (row0 & 31);           // d*32 + c
      int blk = k20 >> 3;
      int off = ij * 2048 + (((blk & ~7) | ((blk & 7) ^ (ij & 7))) * 16) + (k20 & 7) * 2;
      union { unsigned short h[4]; uint2 u; } pk;
      #pragma unroll
      for (int r = 0; r < 4; ++r) pk.h[r] = f2bf(acc[fm][fn][r]);
      *(uint2*)(smem + off) = pk.u;
    }
  __syncthreads();

  // -------- stage 2: z[32 ij][128 e] = O @ Wo; wave (eg,kh): e-slice [eg*32,+32), k2-half kh --------
  const int eg = w >> 1, kh = w & 1;
  const int e0 = eg * 32;
  f32x4 acc2[2][2];                           // [fij][fe]
  #pragma unroll
  for (int p = 0; p < 2; ++p)
    #pragma unroll
    for (int q = 0; q < 2; ++q) acc2[p][q] = (f32x4)0.f;

  #pragma unroll 4
  for (int s = 0; s < 16; ++s) {
    int kk = kh * 16 + s;
    int k = kk * 32 + quad * 8;
    int blk = kk * 4 + quad;
    bf16x8 b[2];
    #pragma unroll
    for (int fe = 0; fe < 2; ++fe)
      b[fe] = *(const bf16x8*)(WoTp + (size_t)(e0 + fe * 16 + mlo) * 1024 + k);
    #pragma unroll
    for (int fij = 0; fij < 2; ++fij) {
      int ij = fij * 16 + mlo;
      bf16x8 a = *(const bf16x8*)(smem + ij * 2048 + (((blk & ~7) | ((blk & 7) ^ (ij & 7))) * 16));
      #pragma unroll
      for (int fe = 0; fe < 2; ++fe)
        acc2[fij][fe] = __builtin_amdgcn_mfma_f32_16x16x32_bf16(a, b[fe], acc2[fij][fe], 0, 0, 0);
    }
  }
  __syncthreads();                       // all O_lds reads done; partials may alias smem

  // -------- cross-k2 reduction: kh=1 writes f32 partials, kh=0 combines --------
  float* partf = (float*)smem;           // [4 eg][32 ij][33] f32 (stride 33 breaks bank conflicts)
  float* red   = (float*)(smem + 16896); // [32 ij][4 eg]
  float* sclp  = (float*)(smem + 17408); // [32]
  if (kh == 1) {
    #pragma unroll
    for (int fij = 0; fij < 2; ++fij)
      #pragma unroll
      for (int fe = 0; fe < 2; ++fe)
        #pragma unroll
        for (int r = 0; r < 4; ++r)
          partf[eg * 1056 + (fij * 16 + quad * 4 + r) * 33 + fe * 16 + mlo] = acc2[fij][fe][r];
  }
  __syncthreads();

  // acc2 C-layout: z[ij = fij*16 + quad*4 + r][e = e0 + fe*16 + mlo]
  float v[2][2][4];
  if (kh == 0) {
    float bv[2], gv[2];
    #pragma unroll
    for (int fe = 0; fe < 2; ++fe) { bv[fe] = bo[e0 + fe * 16 + mlo]; gv[fe] = gout[e0 + fe * 16 + mlo]; }
    float sq[2][4];
    #pragma unroll
    for (int fij = 0; fij < 2; ++fij)
      #pragma unroll
      for (int r = 0; r < 4; ++r) {
        float t = 0.f;
        #pragma unroll
        for (int fe = 0; fe < 2; ++fe) {
          float x = acc2[fij][fe][r] + partf[eg * 1056 + (fij * 16 + quad * 4 + r) * 33 + fe * 16 + mlo] + bv[fe];
          v[fij][fe][r] = x * gv[fe];   // fold g_out early; scale applied after rmsnorm
          t += x * x;
        }
        sq[fij][r] = t;
      }
    #pragma unroll
    for (int o = 1; o < 16; o <<= 1)
      #pragma unroll
      for (int fij = 0; fij < 2; ++fij)
        #pragma unroll
        for (int r = 0; r < 4; ++r) sq[fij][r] += __shfl_xor(sq[fij][r], o, 64);
    if (mlo == 0) {
      #pragma unroll
      for (int fij = 0; fij < 2; ++fij)
        #pragma unroll
        for (int r = 0; r < 4; ++r) red[(fij * 16 + quad * 4 + r) * 4 + eg] = sq[fij][r];
    }
  }
  __syncthreads();
  if (tid < 32) {
    float t = red[tid * 4] + red[tid * 4 + 1] + red[tid * 4 + 2] + red[tid * 4 + 3];
    sclp[tid] = rsqrtf(t * (1.f / 128.f) + EPS);
  }
  __syncthreads();
  if (kh == 0) {
    #pragma unroll
    for (int fij = 0; fij < 2; ++fij)
      #pragma unroll
      for (int r = 0; r < 4; ++r) {
        int ij = fij * 16 + quad * 4 + r;
        float sc = sclp[ij];
        int gi = ti * 8 + (ij >> 2), gj = tj * 4 + (ij & 3);
        #pragma unroll
        for (int fe = 0; fe < 2; ++fe)
          out[((size_t)gi * S + gj) * CZ + e0 + fe * 16 + mlo] = v[fij][fe][r] * sc;
      }
  }
}

// ---------------------------------------------------------------------------------------------------
extern "C" void kernel_launch(void* const* d_in, const int* in_sizes, int n_in,
                              void* d_out, int out_size, void* d_ws, size_t ws_size,
                              hipStream_t stream) {
  const float* m    = (const float*)d_in[0];
  const float* gin  = (const float*)d_in[1];
  const float* Wq   = (const float*)d_in[2];
  const float* bq   = (const float*)d_in[3];
  const float* Wk   = (const float*)d_in[4];
  const float* bk   = (const float*)d_in[5];
  const float* Wo   = (const float*)d_in[6];
  const float* bo   = (const float*)d_in[7];
  const float* gout = (const float*)d_in[8];

  char* ws = (char*)d_ws;
  unsigned short* qT    = (unsigned short*)(ws + OFF_QT);
  unsigned short* kT    = (unsigned short*)(ws + OFF_KT);
  unsigned short* WTg   = (unsigned short*)(ws + OFF_WT);
  unsigned short* WoTp  = (unsigned short*)(ws + OFF_WOT);
  float* out = (float*)d_out;

  hipLaunchKernelGGL(k0_prep, dim3(576), dim3(256), 0, stream, Wq, Wk, Wo, WTg, WoTp);
  hipLaunchKernelGGL(k2_proj, dim3(96, 8), dim3(256), 0, stream, m, gin, WTg, bq, bk, qT, kT);
  hipLaunchKernelGGL(k3_fused, dim3(4608), dim3(512), 0, stream, qT, kT, WoTp, bo, gout, out);
}

// Round 3
// 433.616 us; speedup vs baseline: 1.0185x; 1.0185x over previous
//
#include <hip/hip_runtime.h>
#include <hip/hip_bf16.h>
#include <stdint.h>

#define S   384
#define CM  256
#define CH  32
#define CZ  128
#define BB  256     // MSA depth b = K of GEMM1
#define EPS 1e-5f

typedef __attribute__((ext_vector_type(8))) short bf16x8;   // 8 bf16 = 4 VGPRs
typedef __attribute__((ext_vector_type(4))) float f32x4;

// workspace layout (bytes)
#define OFF_QT    0u                       // [12288][256] bf16 = 6291456  (row = i*32+c, col = b)
#define OFF_KT    6291456u                 // [12288][256] bf16            (row = j*32+d, col = b)
#define OFF_WT    (OFF_KT + 6291456u)      // [64][256] bf16 = 32768
#define OFF_WOT   (OFF_WT + 32768u)        // [128][1024] bf16 = 262144    WoTp[e][d*32+c] = Wo[c*32+d][e]

__device__ __forceinline__ unsigned short f2bf(float x) {
  union { __hip_bfloat16 h; unsigned short u; } v;
  v.h = __float2bfloat16(x);
  return v.u;
}

// async global->LDS, 16B per lane. lds offset wave-uniform; HW scatters lane L to base + L*16.
__device__ __forceinline__ void gload_lds16(const void* g, char* smem, uint32_t lds_off_uniform) {
  uint32_t l32 = (uint32_t)(uintptr_t)(smem + lds_off_uniform);
  __builtin_amdgcn_global_load_lds(
      (const __attribute__((address_space(1))) uint32_t*)(uintptr_t)g,
      (__attribute__((address_space(3))) uint32_t*)(uintptr_t)l32,
      16, 0, 0);
}

// O_lds swizzle, shared by writer (GEMM1 epilogue) and reader (stage 2).
// blk>>3 term: varies per-lane on the write side (spreads banks within one ds_write),
// constant-per-instruction on the read side (blk = kk*4+quad, quad<=3 never crosses an 8-group).
__device__ __forceinline__ int olds_off(int ij, int blk) {
  int slot = (blk & ~7) | (((blk & 7) ^ ((blk >> 3) & 7) ^ (ij & 7)) & 7);
  return ij * 2048 + slot * 16;
}

// ---------------- K0: prep WT (q|k concat, transposed) and WoTp (transposed + k-reordered) ----------
__global__ void k0_prep(const float* __restrict__ Wq, const float* __restrict__ Wk,
                        const float* __restrict__ Wo,
                        unsigned short* __restrict__ WTg, unsigned short* __restrict__ WoTg) {
  int idx = blockIdx.x * 256 + threadIdx.x;
  if (idx < 64 * 256) {
    int c = idx >> 8, t = idx & 255;
    float v = (c < 32) ? Wq[t * 32 + c] : Wk[t * 32 + (c - 32)];
    WTg[c * 256 + t] = f2bf(v);
  }
  int j = idx - 64 * 256;
  if (j >= 0 && j < 128 * 1024) {
    int e = j >> 10, dc = j & 1023;       // dc = d*32 + c  (stage-2 k order)
    int c = dc & 31, d = dc >> 5;
    WoTg[e * 1024 + dc] = f2bf(Wo[(c * 32 + d) * 128 + e]);
  }
}

// ---------------- K2: fused rmsnorm + projection GEMM, writes qT/kT transposed -----------------------
__global__ __launch_bounds__(256, 2) void k2_proj(const float* __restrict__ m,
                                                  const float* __restrict__ gin,
                                                  const unsigned short* __restrict__ WTg,
                                                  const float* __restrict__ bq,
                                                  const float* __restrict__ bk,
                                                  unsigned short* __restrict__ qT,
                                                  unsigned short* __restrict__ kT) {
  // LDS: A [128][64] bf16 swz @0 (16KB) | WT [64][256] swz @16384 (32KB) |
  //      scl[128] f32 @49152 (512B) | Cbuf [128][72] bf16 @49664 (18KB)
  __shared__ char smem[49664 + 18432] __attribute__((aligned(16)));
  const int tid = threadIdx.x;
  const int w = tid >> 6, lane = tid & 63;
  const int mlo = lane & 15, quad = lane >> 4;
  const int i0 = blockIdx.x * 4, b0 = blockIdx.y * 32;
  float* scl = (float*)(smem + 49152);

  #pragma unroll
  for (int s = 0; s < 8; ++s) {
    int C0 = (w * 8 + s) * 2;
    int c = C0 + (lane >> 5);
    int j = lane & 31;
    int t8 = (j & ~7) | ((j & 7) ^ (c & 7));
    gload_lds16(WTg + c * 256 + t8 * 8, smem, 16384u + (uint32_t)C0 * 512u);
  }

  // phase A: per-row sum of squares (fp32), 2 threads per row, 128 floats each
  const int rowA = tid >> 1, halfA = tid & 1;
  const int growA = (b0 + (rowA >> 2)) * S + i0 + (rowA & 3);
  {
    const float4* p = (const float4*)(m + (size_t)growA * CM + halfA * 128);
    float ss = 0.f;
    #pragma unroll 8
    for (int q4 = 0; q4 < 32; ++q4) {
      float4 x = p[q4];
      ss += x.x * x.x + x.y * x.y + x.z * x.z + x.w * x.w;
    }
    ss += __shfl_xor(ss, 1, 64);
    if (!halfA) scl[rowA] = rsqrtf(ss * (1.f / 256.f) + EPS);
  }

  f32x4 acc[2][4];
  #pragma unroll
  for (int p = 0; p < 2; ++p)
    #pragma unroll
    for (int q = 0; q < 4; ++q) acc[p][q] = (f32x4)0.f;

  for (int kb = 0; kb < 4; ++kb) {
    __syncthreads();
    {
      const int row = tid >> 1, tk0 = (tid & 1) * 32;
      const float4* pB = (const float4*)(m + (size_t)growA * CM + kb * 64 + tk0);
      const float4* pG = (const float4*)(gin + kb * 64 + tk0);
      float sc = scl[row];
      #pragma unroll
      for (int u = 0; u < 4; ++u) {
        float4 x0 = pB[u * 2], x1 = pB[u * 2 + 1];
        float4 g0 = pG[u * 2], g1 = pG[u * 2 + 1];
        union { unsigned short h[8]; int4 q; } pk;
        pk.h[0] = f2bf(x0.x * sc * g0.x); pk.h[1] = f2bf(x0.y * sc * g0.y);
        pk.h[2] = f2bf(x0.z * sc * g0.z); pk.h[3] = f2bf(x0.w * sc * g0.w);
        pk.h[4] = f2bf(x1.x * sc * g1.x); pk.h[5] = f2bf(x1.y * sc * g1.y);
        pk.h[6] = f2bf(x1.z * sc * g1.z); pk.h[7] = f2bf(x1.w * sc * g1.w);
        int blkid = (((tid & 1) * 4 + u) ^ (row & 7));
        *(int4*)(smem + row * 128 + blkid * 16) = pk.q;
      }
    }
    __syncthreads();
    #pragma unroll
    for (int ks = 0; ks < 2; ++ks) {
      bf16x8 af[2], bfr[4];
      int k8 = ks * 4 + quad;
      #pragma unroll
      for (int fm = 0; fm < 2; ++fm) {
        int mm = w * 32 + fm * 16 + mlo;
        af[fm] = *(const bf16x8*)(smem + mm * 128 + ((k8 ^ (mm & 7)) * 16));
      }
      #pragma unroll
      for (int fn = 0; fn < 4; ++fn) {
        int c = fn * 16 + mlo;
        int t8 = kb * 8 + ks * 4 + quad;
        bfr[fn] = *(const bf16x8*)(smem + 16384 + c * 512 + (((t8 & ~7) | ((t8 & 7) ^ (c & 7))) * 16));
      }
      #pragma unroll
      for (int fm = 0; fm < 2; ++fm)
        #pragma unroll
        for (int fn = 0; fn < 4; ++fn)
          acc[fm][fn] = __builtin_amdgcn_mfma_f32_16x16x32_bf16(af[fm], bfr[fn], acc[fm][fn], 0, 0, 0);
    }
  }
  __syncthreads();
  unsigned short* Cl = (unsigned short*)(smem + 49664);
  #pragma unroll
  for (int fm = 0; fm < 2; ++fm)
    #pragma unroll
    for (int fn = 0; fn < 4; ++fn) {
      int cc = fn * 16 + mlo;
      float bias = (cc < 32) ? bq[cc] : bk[cc - 32];
      #pragma unroll
      for (int r = 0; r < 4; ++r) {
        int rr = w * 32 + fm * 16 + quad * 4 + r;
        Cl[rr * 72 + cc] = f2bf(acc[fm][fn][r] + bias);
      }
    }
  __syncthreads();
  {
    int il = tid >> 6, cc = tid & 63;
    unsigned short* dst = (cc < 32) ? (qT + ((i0 + il) * 32 + cc) * BB + b0)
                                    : (kT + ((i0 + il) * 32 + (cc - 32)) * BB + b0);
    #pragma unroll
    for (int v = 0; v < 4; ++v) {
      union { unsigned short h[8]; int4 q; } u;
      #pragma unroll
      for (int x = 0; x < 8; ++x) u.h[x] = Cl[((v * 8 + x) * 4 + il) * 72 + cc];
      *(int4*)(dst + v * 8) = u.q;
    }
  }
}

// ---------------- K3: 256x128 O-tile GEMM -> @Wo + bo -> rmsnorm -> z -------------------------------
// 512 threads = 8 waves. GEMM1: wave grid 4(m) x 2(n), wave-tile 64x64, frags 4x4.
// launch_bounds(512, 2): 256-reg/wave budget — acc(64 AGPR)+acc2(16)+af2 pre-read(32)+bfr(16)+addr
// needs ~170; the old (512,4) bound capped at 128 and spilled to scratch (was +350MB HBM traffic).
// Occupancy is LDS-limited at 2 blocks/CU either way.
__global__ __launch_bounds__(512, 2) void k3_fused(const unsigned short* __restrict__ qT,
                                                   const unsigned short* __restrict__ kT,
                                                   const unsigned short* __restrict__ WoTp,
                                                   const float* __restrict__ bo,
                                                   const float* __restrict__ gout,
                                                   float* __restrict__ out) {
  // LDS 64KB: GEMM1: A-tile [256][64] swz @0 (32KB) | B-tile x2 [128][64] swz @32768/@49152 (16KB each).
  // After GEMM1 the whole 64KB aliases O_lds [32 ij][1024 k2'] bf16 (k2' = d*32+c, swizzled).
  // After stage-2 reads complete, [0,16896) aliases part[4][32][33] f32; red/scl above that.
  __shared__ char smem[65536] __attribute__((aligned(16)));
  const int tid = threadIdx.x;
  const int w = tid >> 6, lane = tid & 63;
  const int wm = w & 3, wn = w >> 2;          // GEMM1 wave grid 4 (m) x 2 (n)
  const int mlo = lane & 15, quad = lane >> 4;

  // XCD-aware swizzle: consecutive blockIdx round-robin XCDs; give each XCD a contiguous
  // 48(ti) x 12(tj) band so kT-band (768KB) + WoTp (256KB) stay L2-resident per XCD.
  const int bid = blockIdx.x;                 // 0..4607
  const int xcd = bid & 7, idx = bid >> 3;    // idx 0..575
  const int ti = idx / 12;                    // 0..47  (A-panel reused by 12 consecutive blocks)
  const int tj = xcd * 12 + (idx % 12);       // 0..95

  f32x4 acc[4][4];
  #pragma unroll
  for (int p = 0; p < 4; ++p)
    #pragma unroll
    for (int q = 0; q < 4; ++q) acc[p][q] = (f32x4)0.f;

  // -------- GEMM1: O[m][n] = sum_b qT[ti*256+m][b] * kT[tj*128+n][b], K=256, BK=64 --------
  auto stageA = [&](int kb) {
    #pragma unroll
    for (int s = 0; s < 4; ++s) {            // A-tile: wave w stages rows [w*32, w*32+32)
      int r = w * 32 + s * 8 + (lane >> 3);
      int k8 = (lane & 7) ^ (r & 7);
      gload_lds16(qT + (ti * 256 + r) * BB + kb * 64 + k8 * 8, smem, (uint32_t)(w * 32 + s * 8) * 128u);
    }
  };
  auto stageB = [&](int kb, int bsel) {
    #pragma unroll
    for (int s = 0; s < 2; ++s) {            // B-tile: wave w stages rows [w*16, w*16+16)
      int r = w * 16 + s * 8 + (lane >> 3);
      int k8 = (lane & 7) ^ (r & 7);
      gload_lds16(kT + (tj * 128 + r) * BB + kb * 64 + k8 * 8, smem,
                  32768u + (uint32_t)bsel * 16384u + (uint32_t)(w * 16 + s * 8) * 128u);
    }
  };

  stageA(0); stageB(0, 0);
  __syncthreads();                           // implicit vmcnt(0) drain: kb=0 tiles landed

  for (int kb = 0; kb < 4; ++kb) {
    const int bsel = kb & 1;
    // pre-read ALL A-frags for this kb into regs (A buffer about to be overwritten)
    bf16x8 af2[2][4];
    #pragma unroll
    for (int ks = 0; ks < 2; ++ks)
      #pragma unroll
      for (int f = 0; f < 4; ++f) {
        int k8 = ks * 4 + quad;
        int mm = wm * 64 + f * 16 + mlo;
        af2[ks][f] = *(const bf16x8*)(smem + mm * 128 + ((k8 ^ (mm & 7)) * 16));
      }
    __syncthreads();                         // implicit lgkmcnt(0): all waves' A-reads in regs
    if (kb < 3) { stageA(kb + 1); stageB(kb + 1, bsel ^ 1); }  // in flight across MFMAs below
    #pragma unroll
    for (int ks = 0; ks < 2; ++ks) {
      bf16x8 bfr[4];
      int k8 = ks * 4 + quad;
      #pragma unroll
      for (int f = 0; f < 4; ++f) {
        int nn = wn * 64 + f * 16 + mlo;
        bfr[f] = *(const bf16x8*)(smem + 32768 + bsel * 16384 + nn * 128 + ((k8 ^ (nn & 7)) * 16));
      }
      #pragma unroll
      for (int fm = 0; fm < 4; ++fm)
        #pragma unroll
        for (int fn = 0; fn < 4; ++fn)
          acc[fm][fn] = __builtin_amdgcn_mfma_f32_16x16x32_bf16(af2[ks][fm], bfr[fn], acc[fm][fn], 0, 0, 0);
    }
    __syncthreads();                         // implicit vmcnt(0): kb+1 tiles landed (hidden by MFMAs)
  }

  // -------- O (C-layout regs) -> O_lds[ij][k2'] bf16, k2' = d*32 + c; packed 8B writes --------
  #pragma unroll
  for (int fm = 0; fm < 4; ++fm)
    #pragma unroll
    for (int fn = 0; fn < 4; ++fn) {
      int col = wn * 64 + fn * 16 + mlo;                 // n = jloc*32 + d  (0..127)
      int row0 = wm * 64 + fm * 16 + quad * 4;           // m = iloc*32 + c  (0..255)
      int ij = (row0 >> 5) * 4 + (col >> 5);             // iloc*4 + jloc    (0..31)
      int k20 = (col & 31) * 32 + (row0 & 31);           // d*32 + c
      int blk = k20 >> 3;
      int off = olds_off(ij, blk) + (k20 & 7) * 2;
      union { unsigned short h[4]; uint2 u; } pk;
      #pragma unroll
      for (int r = 0; r < 4; ++r) pk.h[r] = f2bf(acc[fm][fn][r]);
      *(uint2*)(smem + off) = pk.u;
    }
  __syncthreads();

  // -------- stage 2: z[32 ij][128 e] = O @ Wo; wave (eg,kh): e-slice [eg*32,+32), k2-half kh --------
  const int eg = w >> 1, kh = w & 1;
  const int e0 = eg * 32;
  f32x4 acc2[2][2];                           // [fij][fe]
  #pragma unroll
  for (int p = 0; p < 2; ++p)
    #pragma unroll
    for (int q = 0; q < 2; ++q) acc2[p][q] = (f32x4)0.f;

  #pragma unroll 4
  for (int s = 0; s < 16; ++s) {
    int kk = kh * 16 + s;
    int k = kk * 32 + quad * 8;
    int blk = kk * 4 + quad;
    bf16x8 b[2];
    #pragma unroll
    for (int fe = 0; fe < 2; ++fe)
      b[fe] = *(const bf16x8*)(WoTp + (size_t)(e0 + fe * 16 + mlo) * 1024 + k);
    #pragma unroll
    for (int fij = 0; fij < 2; ++fij) {
      int ij = fij * 16 + mlo;
      bf16x8 a = *(const bf16x8*)(smem + olds_off(ij, blk));
      #pragma unroll
      for (int fe = 0; fe < 2; ++fe)
        acc2[fij][fe] = __builtin_amdgcn_mfma_f32_16x16x32_bf16(a, b[fe], acc2[fij][fe], 0, 0, 0);
    }
  }
  __syncthreads();                       // all O_lds reads done; partials may alias smem

  // -------- cross-k2 reduction: kh=1 writes f32 partials, kh=0 combines --------
  float* partf = (float*)smem;           // [4 eg][32 ij][33] f32 (stride 33 breaks bank conflicts)
  float* red   = (float*)(smem + 16896); // [32 ij][4 eg]
  float* sclp  = (float*)(smem + 17408); // [32]
  if (kh == 1) {
    #pragma unroll
    for (int fij = 0; fij < 2; ++fij)
      #pragma unroll
      for (int fe = 0; fe < 2; ++fe)
        #pragma unroll
        for (int r = 0; r < 4; ++r)
          partf[eg * 1056 + (fij * 16 + quad * 4 + r) * 33 + fe * 16 + mlo] = acc2[fij][fe][r];
  }
  __syncthreads();

  // acc2 C-layout: z[ij = fij*16 + quad*4 + r][e = e0 + fe*16 + mlo]
  float v[2][2][4];
  if (kh == 0) {
    float bv[2], gv[2];
    #pragma unroll
    for (int fe = 0; fe < 2; ++fe) { bv[fe] = bo[e0 + fe * 16 + mlo]; gv[fe] = gout[e0 + fe * 16 + mlo]; }
    float sq[2][4];
    #pragma unroll
    for (int fij = 0; fij < 2; ++fij)
      #pragma unroll
      for (int r = 0; r < 4; ++r) {
        float t = 0.f;
        #pragma unroll
        for (int fe = 0; fe < 2; ++fe) {
          float x = acc2[fij][fe][r] + partf[eg * 1056 + (fij * 16 + quad * 4 + r) * 33 + fe * 16 + mlo] + bv[fe];
          v[fij][fe][r] = x * gv[fe];   // fold g_out early; scale applied after rmsnorm
          t += x * x;
        }
        sq[fij][r] = t;
      }
    #pragma unroll
    for (int o = 1; o < 16; o <<= 1)
      #pragma unroll
      for (int fij = 0; fij < 2; ++fij)
        #pragma unroll
        for (int r = 0; r < 4; ++r) sq[fij][r] += __shfl_xor(sq[fij][r], o, 64);
    if (mlo == 0) {
      #pragma unroll
      for (int fij = 0; fij < 2; ++fij)
        #pragma unroll
        for (int r = 0; r < 4; ++r) red[(fij * 16 + quad * 4 + r) * 4 + eg] = sq[fij][r];
    }
  }
  __syncthreads();
  if (tid < 32) {
    float t = red[tid * 4] + red[tid * 4 + 1] + red[tid * 4 + 2] + red[tid * 4 + 3];
    sclp[tid] = rsqrtf(t * (1.f / 128.f) + EPS);
  }
  __syncthreads();
  if (kh == 0) {
    #pragma unroll
    for (int fij = 0; fij < 2; ++fij)
      #pragma unroll
      for (int r = 0; r < 4; ++r) {
        int ij = fij * 16 + quad * 4 + r;
        float sc = sclp[ij];
        int gi = ti * 8 + (ij >> 2), gj = tj * 4 + (ij & 3);
        #pragma unroll
        for (int fe = 0; fe < 2; ++fe)
          out[((size_t)gi * S + gj) * CZ + e0 + fe * 16 + mlo] = v[fij][fe][r] * sc;
      }
  }
}

// ---------------------------------------------------------------------------------------------------
extern "C" void kernel_launch(void* const* d_in, const int* in_sizes, int n_in,
                              void* d_out, int out_size, void* d_ws, size_t ws_size,
                              hipStream_t stream) {
  const float* m    = (const float*)d_in[0];
  const float* gin  = (const float*)d_in[1];
  const float* Wq   = (const float*)d_in[2];
  const float* bq   = (const float*)d_in[3];
  const float* Wk   = (const float*)d_in[4];
  const float* bk   = (const float*)d_in[5];
  const float* Wo   = (const float*)d_in[6];
  const float* bo   = (const float*)d_in[7];
  const float* gout = (const float*)d_in[8];

  char* ws = (char*)d_ws;
  unsigned short* qT    = (unsigned short*)(ws + OFF_QT);
  unsigned short* kT    = (unsigned short*)(ws + OFF_KT);
  unsigned short* WTg   = (unsigned short*)(ws + OFF_WT);
  unsigned short* WoTp  = (unsigned short*)(ws + OFF_WOT);
  float* out = (float*)d_out;

  hipLaunchKernelGGL(k0_prep, dim3(576), dim3(256), 0, stream, Wq, Wk, Wo, WTg, WoTp);
  hipLaunchKernelGGL(k2_proj, dim3(96, 8), dim3(256), 0, stream, m, gin, WTg, bq, bk, qT, kT);
  hipLaunchKernelGGL(k3_fused, dim3(4608), dim3(512), 0, stream, qT, kT, WoTp, bo, gout, out);
}

// Round 4
// 389.958 us; speedup vs baseline: 1.1326x; 1.1120x over previous
//
#include <hip/hip_runtime.h>
#include <hip/hip_bf16.h>
#include <stdint.h>

#define S   384
#define CM  256
#define CH  32
#define CZ  128
#define BB  256     // MSA depth b = K of GEMM1
#define EPS 1e-5f

typedef __attribute__((ext_vector_type(8))) short bf16x8;   // 8 bf16 = 4 VGPRs
typedef __attribute__((ext_vector_type(4))) float f32x4;

// workspace layout (bytes)
#define OFF_QT    0u                       // [12288][256] bf16 = 6291456  (row = i*32+c, col = b)
#define OFF_KT    6291456u                 // [12288][256] bf16            (row = j*32+d, col = b)
#define OFF_WT    (OFF_KT + 6291456u)      // [64][256] bf16 = 32768
#define OFF_WOT   (OFF_WT + 32768u)        // [128][1024] bf16 = 262144    WoTp[e][d*32+c] = Wo[c*32+d][e]

__device__ __forceinline__ unsigned short f2bf(float x) {
  union { __hip_bfloat16 h; unsigned short u; } v;
  v.h = __float2bfloat16(x);
  return v.u;
}

// async global->LDS, 16B per lane. lds offset wave-uniform; HW scatters lane L to base + L*16.
__device__ __forceinline__ void gload_lds16(const void* g, char* smem, uint32_t lds_off_uniform) {
  uint32_t l32 = (uint32_t)(uintptr_t)(smem + lds_off_uniform);
  __builtin_amdgcn_global_load_lds(
      (const __attribute__((address_space(1))) uint32_t*)(uintptr_t)g,
      (__attribute__((address_space(3))) uint32_t*)(uintptr_t)l32,
      16, 0, 0);
}

// O_lds swizzle, shared by writer (GEMM1 epilogue) and reader (stage 2).
// blk>>3 term: varies per-lane on the write side (spreads banks within one ds_write),
// constant-per-instruction on the read side (blk = kk*4+quad, quad<=3 never crosses an 8-group).
__device__ __forceinline__ int olds_off(int ij, int blk) {
  int slot = (blk & ~7) | (((blk & 7) ^ ((blk >> 3) & 7) ^ (ij & 7)) & 7);
  return ij * 2048 + slot * 16;
}

// ---------------- K0: prep WT (q|k concat, transposed) and WoTp (transposed + k-reordered) ----------
__global__ void k0_prep(const float* __restrict__ Wq, const float* __restrict__ Wk,
                        const float* __restrict__ Wo,
                        unsigned short* __restrict__ WTg, unsigned short* __restrict__ WoTg) {
  int idx = blockIdx.x * 256 + threadIdx.x;
  if (idx < 64 * 256) {
    int c = idx >> 8, t = idx & 255;
    float v = (c < 32) ? Wq[t * 32 + c] : Wk[t * 32 + (c - 32)];
    WTg[c * 256 + t] = f2bf(v);
  }
  int j = idx - 64 * 256;
  if (j >= 0 && j < 128 * 1024) {
    int e = j >> 10, dc = j & 1023;       // dc = d*32 + c  (stage-2 k order)
    int c = dc & 31, d = dc >> 5;
    WoTg[e * 1024 + dc] = f2bf(Wo[(c * 32 + d) * 128 + e]);
  }
}

// ---------------- K2: fused rmsnorm + projection GEMM, writes qT/kT transposed -----------------------
// LDS trimmed to 49.7KB (Cbuf aliases the dead A/WT region) -> 3 blocks/CU for latency hiding.
__global__ __launch_bounds__(256, 3) void k2_proj(const float* __restrict__ m,
                                                  const float* __restrict__ gin,
                                                  const unsigned short* __restrict__ WTg,
                                                  const float* __restrict__ bq,
                                                  const float* __restrict__ bk,
                                                  unsigned short* __restrict__ qT,
                                                  unsigned short* __restrict__ kT) {
  // LDS: A [128][64] bf16 swz @0 (16KB) | WT [64][256] swz @16384 (32KB) |
  //      scl[128] f32 @49152 (512B). Cbuf [128][72] bf16 ALIASES @0 after the MFMA loop.
  __shared__ char smem[49664] __attribute__((aligned(16)));
  const int tid = threadIdx.x;
  const int w = tid >> 6, lane = tid & 63;
  const int mlo = lane & 15, quad = lane >> 4;
  const int i0 = blockIdx.x * 4, b0 = blockIdx.y * 32;
  float* scl = (float*)(smem + 49152);

  #pragma unroll
  for (int s = 0; s < 8; ++s) {
    int C0 = (w * 8 + s) * 2;
    int c = C0 + (lane >> 5);
    int j = lane & 31;
    int t8 = (j & ~7) | ((j & 7) ^ (c & 7));
    gload_lds16(WTg + c * 256 + t8 * 8, smem, 16384u + (uint32_t)C0 * 512u);
  }

  // phase A: per-row sum of squares (fp32), 2 threads per row, 128 floats each
  const int rowA = tid >> 1, halfA = tid & 1;
  const int growA = (b0 + (rowA >> 2)) * S + i0 + (rowA & 3);
  {
    const float4* p = (const float4*)(m + (size_t)growA * CM + halfA * 128);
    float ss = 0.f;
    #pragma unroll 8
    for (int q4 = 0; q4 < 32; ++q4) {
      float4 x = p[q4];
      ss += x.x * x.x + x.y * x.y + x.z * x.z + x.w * x.w;
    }
    ss += __shfl_xor(ss, 1, 64);
    if (!halfA) scl[rowA] = rsqrtf(ss * (1.f / 256.f) + EPS);
  }

  f32x4 acc[2][4];
  #pragma unroll
  for (int p = 0; p < 2; ++p)
    #pragma unroll
    for (int q = 0; q < 4; ++q) acc[p][q] = (f32x4)0.f;

  for (int kb = 0; kb < 4; ++kb) {
    __syncthreads();
    {
      const int row = tid >> 1, tk0 = (tid & 1) * 32;
      const float4* pB = (const float4*)(m + (size_t)growA * CM + kb * 64 + tk0);
      const float4* pG = (const float4*)(gin + kb * 64 + tk0);
      float sc = scl[row];
      #pragma unroll
      for (int u = 0; u < 4; ++u) {
        float4 x0 = pB[u * 2], x1 = pB[u * 2 + 1];
        float4 g0 = pG[u * 2], g1 = pG[u * 2 + 1];
        union { unsigned short h[8]; int4 q; } pk;
        pk.h[0] = f2bf(x0.x * sc * g0.x); pk.h[1] = f2bf(x0.y * sc * g0.y);
        pk.h[2] = f2bf(x0.z * sc * g0.z); pk.h[3] = f2bf(x0.w * sc * g0.w);
        pk.h[4] = f2bf(x1.x * sc * g1.x); pk.h[5] = f2bf(x1.y * sc * g1.y);
        pk.h[6] = f2bf(x1.z * sc * g1.z); pk.h[7] = f2bf(x1.w * sc * g1.w);
        int blkid = (((tid & 1) * 4 + u) ^ (row & 7));
        *(int4*)(smem + row * 128 + blkid * 16) = pk.q;
      }
    }
    __syncthreads();
    #pragma unroll
    for (int ks = 0; ks < 2; ++ks) {
      bf16x8 af[2], bfr[4];
      int k8 = ks * 4 + quad;
      #pragma unroll
      for (int fm = 0; fm < 2; ++fm) {
        int mm = w * 32 + fm * 16 + mlo;
        af[fm] = *(const bf16x8*)(smem + mm * 128 + ((k8 ^ (mm & 7)) * 16));
      }
      #pragma unroll
      for (int fn = 0; fn < 4; ++fn) {
        int c = fn * 16 + mlo;
        int t8 = kb * 8 + ks * 4 + quad;
        bfr[fn] = *(const bf16x8*)(smem + 16384 + c * 512 + (((t8 & ~7) | ((t8 & 7) ^ (c & 7))) * 16));
      }
      #pragma unroll
      for (int fm = 0; fm < 2; ++fm)
        #pragma unroll
        for (int fn = 0; fn < 4; ++fn)
          acc[fm][fn] = __builtin_amdgcn_mfma_f32_16x16x32_bf16(af[fm], bfr[fn], acc[fm][fn], 0, 0, 0);
    }
  }
  __syncthreads();                       // all LDS reads done; Cbuf may alias A/WT region
  unsigned short* Cl = (unsigned short*)smem;
  #pragma unroll
  for (int fm = 0; fm < 2; ++fm)
    #pragma unroll
    for (int fn = 0; fn < 4; ++fn) {
      int cc = fn * 16 + mlo;
      float bias = (cc < 32) ? bq[cc] : bk[cc - 32];
      #pragma unroll
      for (int r = 0; r < 4; ++r) {
        int rr = w * 32 + fm * 16 + quad * 4 + r;
        Cl[rr * 72 + cc] = f2bf(acc[fm][fn][r] + bias);
      }
    }
  __syncthreads();
  {
    int il = tid >> 6, cc = tid & 63;
    unsigned short* dst = (cc < 32) ? (qT + ((i0 + il) * 32 + cc) * BB + b0)
                                    : (kT + ((i0 + il) * 32 + (cc - 32)) * BB + b0);
    #pragma unroll
    for (int v = 0; v < 4; ++v) {
      union { unsigned short h[8]; int4 q; } u;
      #pragma unroll
      for (int x = 0; x < 8; ++x) u.h[x] = Cl[((v * 8 + x) * 4 + il) * 72 + cc];
      *(int4*)(dst + v * 8) = u.q;
    }
  }
}

// ---------------- K3: 256x128 O-tile GEMM -> @Wo + bo -> rmsnorm -> z -------------------------------
// 512 threads = 8 waves. GEMM1: wave grid 4(m) x 2(n), wave-tile 64x64, frags 4x4.
// Register diet for TRUE 2 blocks/CU under (512,4): no bulk A pre-read. Per kb:
//   read ks0 A+B frags -> MFMA ks0 -> read ks1 A frags (A consumed) -> barrier ->
//   issue stage(kb+1) -> read ks1 B (dbuf, still valid) -> MFMA ks1 (shadows loads) -> barrier.
// Peak live frags 32 regs; arch VGPR target <=64 so arch+64 AGPR <= 128.
__global__ __launch_bounds__(512, 4) void k3_fused(const unsigned short* __restrict__ qT,
                                                   const unsigned short* __restrict__ kT,
                                                   const unsigned short* __restrict__ WoTp,
                                                   const float* __restrict__ bo,
                                                   const float* __restrict__ gout,
                                                   float* __restrict__ out) {
  // LDS 64KB: GEMM1: A-tile [256][64] swz @0 (32KB) | B-tile x2 [128][64] swz @32768/@49152 (16KB each).
  // After GEMM1 the whole 64KB aliases O_lds [32 ij][1024 k2'] bf16 (k2' = d*32+c, swizzled).
  // After stage-2 reads complete, [0,16896) aliases part[4][32][33] f32; red/scl above that.
  __shared__ char smem[65536] __attribute__((aligned(16)));
  const int tid = threadIdx.x;
  const int w = tid >> 6, lane = tid & 63;
  const int wm = w & 3, wn = w >> 2;          // GEMM1 wave grid 4 (m) x 2 (n)
  const int mlo = lane & 15, quad = lane >> 4;

  // XCD-aware swizzle: consecutive blockIdx round-robin XCDs; give each XCD a contiguous
  // 48(ti) x 12(tj) band so kT-band (768KB) + WoTp (256KB) stay L2-resident per XCD.
  const int bid = blockIdx.x;                 // 0..4607
  const int xcd = bid & 7, idx = bid >> 3;    // idx 0..575
  const int ti = idx / 12;                    // 0..47  (A-panel reused by 12 consecutive blocks)
  const int tj = xcd * 12 + (idx % 12);       // 0..95

  f32x4 acc[4][4];
  #pragma unroll
  for (int p = 0; p < 4; ++p)
    #pragma unroll
    for (int q = 0; q < 4; ++q) acc[p][q] = (f32x4)0.f;

  // -------- GEMM1: O[m][n] = sum_b qT[ti*256+m][b] * kT[tj*128+n][b], K=256, BK=64 --------
  auto stageA = [&](int kb) {
    #pragma unroll
    for (int s = 0; s < 4; ++s) {            // A-tile: wave w stages rows [w*32, w*32+32)
      int r = w * 32 + s * 8 + (lane >> 3);
      int k8 = (lane & 7) ^ (r & 7);
      gload_lds16(qT + (ti * 256 + r) * BB + kb * 64 + k8 * 8, smem, (uint32_t)(w * 32 + s * 8) * 128u);
    }
  };
  auto stageB = [&](int kb, int bsel) {
    #pragma unroll
    for (int s = 0; s < 2; ++s) {            // B-tile: wave w stages rows [w*16, w*16+16)
      int r = w * 16 + s * 8 + (lane >> 3);
      int k8 = (lane & 7) ^ (r & 7);
      gload_lds16(kT + (tj * 128 + r) * BB + kb * 64 + k8 * 8, smem,
                  32768u + (uint32_t)bsel * 16384u + (uint32_t)(w * 16 + s * 8) * 128u);
    }
  };

  stageA(0); stageB(0, 0);
  __syncthreads();                           // implicit vmcnt(0) drain: kb=0 tiles landed

  for (int kb = 0; kb < 4; ++kb) {
    const int bsel = kb & 1;
    bf16x8 afr[4], bfr[4];
    // ---- ks0: A+B frag reads, 16 MFMAs ----
    #pragma unroll
    for (int f = 0; f < 4; ++f) {
      int mm = wm * 64 + f * 16 + mlo;
      afr[f] = *(const bf16x8*)(smem + mm * 128 + ((quad ^ (mm & 7)) * 16));
    }
    #pragma unroll
    for (int f = 0; f < 4; ++f) {
      int nn = wn * 64 + f * 16 + mlo;
      bfr[f] = *(const bf16x8*)(smem + 32768 + bsel * 16384 + nn * 128 + ((quad ^ (nn & 7)) * 16));
    }
    #pragma unroll
    for (int fm = 0; fm < 4; ++fm)
      #pragma unroll
      for (int fn = 0; fn < 4; ++fn)
        acc[fm][fn] = __builtin_amdgcn_mfma_f32_16x16x32_bf16(afr[fm], bfr[fn], acc[fm][fn], 0, 0, 0);
    // ---- ks1 A reads (A-tile fully consumed after these) ----
    bf16x8 af1[4];
    #pragma unroll
    for (int f = 0; f < 4; ++f) {
      int mm = wm * 64 + f * 16 + mlo;
      af1[f] = *(const bf16x8*)(smem + mm * 128 + (((4 + quad) ^ (mm & 7)) * 16));
    }
    __syncthreads();                         // all waves' A reads done; A buf may be overwritten
    if (kb < 3) { stageA(kb + 1); stageB(kb + 1, bsel ^ 1); }  // in flight across ks1 MFMAs
    // ---- ks1: B reads from current dbuf (not being written), 16 MFMAs ----
    #pragma unroll
    for (int f = 0; f < 4; ++f) {
      int nn = wn * 64 + f * 16 + mlo;
      bfr[f] = *(const bf16x8*)(smem + 32768 + bsel * 16384 + nn * 128 + (((4 + quad) ^ (nn & 7)) * 16));
    }
    #pragma unroll
    for (int fm = 0; fm < 4; ++fm)
      #pragma unroll
      for (int fn = 0; fn < 4; ++fn)
        acc[fm][fn] = __builtin_amdgcn_mfma_f32_16x16x32_bf16(af1[fm], bfr[fn], acc[fm][fn], 0, 0, 0);
    __syncthreads();                         // implicit vmcnt(0): kb+1 tiles landed (shadowed by MFMAs)
  }

  // -------- O (C-layout regs) -> O_lds[ij][k2'] bf16, k2' = d*32 + c; packed 8B writes --------
  #pragma unroll
  for (int fm = 0; fm < 4; ++fm)
    #pragma unroll
    for (int fn = 0; fn < 4; ++fn) {
      int col = wn * 64 + fn * 16 + mlo;                 // n = jloc*32 + d  (0..127)
      int row0 = wm * 64 + fm * 16 + quad * 4;           // m = iloc*32 + c  (0..255)
      int ij = (row0 >> 5) * 4 + (col >> 5);             // iloc*4 + jloc    (0..31)
      int k20 = (col & 31) * 32 + (row0 & 31);           // d*32 + c
      int blk = k20 >> 3;
      int off = olds_off(ij, blk) + (k20 & 7) * 2;
      union { unsigned short h[4]; uint2 u; } pk;
      #pragma unroll
      for (int r = 0; r < 4; ++r) pk.h[r] = f2bf(acc[fm][fn][r]);
      *(uint2*)(smem + off) = pk.u;
    }
  __syncthreads();

  // -------- stage 2: z[32 ij][128 e] = O @ Wo; wave (eg,kh): e-slice [eg*32,+32), k2-half kh --------
  const int eg = w >> 1, kh = w & 1;
  const int e0 = eg * 32;
  f32x4 acc2[2][2];                           // [fij][fe]
  #pragma unroll
  for (int p = 0; p < 2; ++p)
    #pragma unroll
    for (int q = 0; q < 2; ++q) acc2[p][q] = (f32x4)0.f;

  #pragma unroll 4
  for (int s = 0; s < 16; ++s) {
    int kk = kh * 16 + s;
    int k = kk * 32 + quad * 8;
    int blk = kk * 4 + quad;
    bf16x8 b[2];
    #pragma unroll
    for (int fe = 0; fe < 2; ++fe)
      b[fe] = *(const bf16x8*)(WoTp + (size_t)(e0 + fe * 16 + mlo) * 1024 + k);
    #pragma unroll
    for (int fij = 0; fij < 2; ++fij) {
      int ij = fij * 16 + mlo;
      bf16x8 a = *(const bf16x8*)(smem + olds_off(ij, blk));
      #pragma unroll
      for (int fe = 0; fe < 2; ++fe)
        acc2[fij][fe] = __builtin_amdgcn_mfma_f32_16x16x32_bf16(a, b[fe], acc2[fij][fe], 0, 0, 0);
    }
  }
  __syncthreads();                       // all O_lds reads done; partials may alias smem

  // -------- cross-k2 reduction: kh=1 writes f32 partials, kh=0 combines --------
  float* partf = (float*)smem;           // [4 eg][32 ij][33] f32 (stride 33 breaks bank conflicts)
  float* red   = (float*)(smem + 16896); // [32 ij][4 eg]
  float* sclp  = (float*)(smem + 17408); // [32]
  if (kh == 1) {
    #pragma unroll
    for (int fij = 0; fij < 2; ++fij)
      #pragma unroll
      for (int fe = 0; fe < 2; ++fe)
        #pragma unroll
        for (int r = 0; r < 4; ++r)
          partf[eg * 1056 + (fij * 16 + quad * 4 + r) * 33 + fe * 16 + mlo] = acc2[fij][fe][r];
  }
  __syncthreads();

  // acc2 C-layout: z[ij = fij*16 + quad*4 + r][e = e0 + fe*16 + mlo]
  float v[2][2][4];
  if (kh == 0) {
    float bv[2], gv[2];
    #pragma unroll
    for (int fe = 0; fe < 2; ++fe) { bv[fe] = bo[e0 + fe * 16 + mlo]; gv[fe] = gout[e0 + fe * 16 + mlo]; }
    float sq[2][4];
    #pragma unroll
    for (int fij = 0; fij < 2; ++fij)
      #pragma unroll
      for (int r = 0; r < 4; ++r) {
        float t = 0.f;
        #pragma unroll
        for (int fe = 0; fe < 2; ++fe) {
          float x = acc2[fij][fe][r] + partf[eg * 1056 + (fij * 16 + quad * 4 + r) * 33 + fe * 16 + mlo] + bv[fe];
          v[fij][fe][r] = x * gv[fe];   // fold g_out early; scale applied after rmsnorm
          t += x * x;
        }
        sq[fij][r] = t;
      }
    #pragma unroll
    for (int o = 1; o < 16; o <<= 1)
      #pragma unroll
      for (int fij = 0; fij < 2; ++fij)
        #pragma unroll
        for (int r = 0; r < 4; ++r) sq[fij][r] += __shfl_xor(sq[fij][r], o, 64);
    if (mlo == 0) {
      #pragma unroll
      for (int fij = 0; fij < 2; ++fij)
        #pragma unroll
        for (int r = 0; r < 4; ++r) red[(fij * 16 + quad * 4 + r) * 4 + eg] = sq[fij][r];
    }
  }
  __syncthreads();
  if (tid < 32) {
    float t = red[tid * 4] + red[tid * 4 + 1] + red[tid * 4 + 2] + red[tid * 4 + 3];
    sclp[tid] = rsqrtf(t * (1.f / 128.f) + EPS);
  }
  __syncthreads();
  if (kh == 0) {
    #pragma unroll
    for (int fij = 0; fij < 2; ++fij)
      #pragma unroll
      for (int r = 0; r < 4; ++r) {
        int ij = fij * 16 + quad * 4 + r;
        float sc = sclp[ij];
        int gi = ti * 8 + (ij >> 2), gj = tj * 4 + (ij & 3);
        #pragma unroll
        for (int fe = 0; fe < 2; ++fe)
          out[((size_t)gi * S + gj) * CZ + e0 + fe * 16 + mlo] = v[fij][fe][r] * sc;
      }
  }
}

// ---------------------------------------------------------------------------------------------------
extern "C" void kernel_launch(void* const* d_in, const int* in_sizes, int n_in,
                              void* d_out, int out_size, void* d_ws, size_t ws_size,
                              hipStream_t stream) {
  const float* m    = (const float*)d_in[0];
  const float* gin  = (const float*)d_in[1];
  const float* Wq   = (const float*)d_in[2];
  const float* bq   = (const float*)d_in[3];
  const float* Wk   = (const float*)d_in[4];
  const float* bk   = (const float*)d_in[5];
  const float* Wo   = (const float*)d_in[6];
  const float* bo   = (const float*)d_in[7];
  const float* gout = (const float*)d_in[8];

  char* ws = (char*)d_ws;
  unsigned short* qT    = (unsigned short*)(ws + OFF_QT);
  unsigned short* kT    = (unsigned short*)(ws + OFF_KT);
  unsigned short* WTg   = (unsigned short*)(ws + OFF_WT);
  unsigned short* WoTp  = (unsigned short*)(ws + OFF_WOT);
  float* out = (float*)d_out;

  hipLaunchKernelGGL(k0_prep, dim3(576), dim3(256), 0, stream, Wq, Wk, Wo, WTg, WoTp);
  hipLaunchKernelGGL(k2_proj, dim3(96, 8), dim3(256), 0, stream, m, gin, WTg, bq, bk, qT, kT);
  hipLaunchKernelGGL(k3_fused, dim3(4608), dim3(512), 0, stream, qT, kT, WoTp, bo, gout, out);
}